// Round 3
// baseline (2241.552 us; speedup 1.0000x reference)
//
#include <hip/hip_runtime.h>
#include <math.h>

#define NC 2000
#define NP 1500
#define NA 40
#define LP 512
#define BSZ 4096

// ======================= GNN (fused per compound) =======================
__global__ __launch_bounds__(320) void gnn_kernel(
    const int* __restrict__ compounds, const float* __restrict__ adjacencies,
    const float* __restrict__ embed_fp, const float* __restrict__ W_gnn,
    const float* __restrict__ b_gnn, float* __restrict__ comp_int)
{
    __shared__ float xs[40][68];
    __shared__ float hs[40][68];
    __shared__ float Ws[64][64];
    __shared__ float adjS[40][41];
    __shared__ float bS[64];
    const int n = blockIdx.x;
    const int tid = threadIdx.x;
    const int a = tid >> 3, g = tid & 7, cb = g * 8;

    for (int j = tid; j < 40 * 64; j += 320) {
        int r = j >> 6, c = j & 63;
        xs[r][c] = embed_fp[(size_t)compounds[n * NA + r] * 64 + c];
    }
    for (int j = tid; j < NA * NA; j += 320)
        adjS[j / NA][j % NA] = adjacencies[(size_t)n * (NA * NA) + j];

    for (int l = 0; l < 3; ++l) {
        __syncthreads();  // xs/adj ready (l=0) or prev layer fully done; Ws free
        for (int j = tid; j < 4096; j += 320) Ws[j >> 6][j & 63] = W_gnn[l * 4096 + j];
        if (tid < 64) bS[tid] = b_gnn[l * 64 + tid];
        __syncthreads();
        // hs = relu(xs @ W + b)
        float acc[8];
        #pragma unroll
        for (int j = 0; j < 8; ++j) acc[j] = bS[cb + j];
        #pragma unroll 8
        for (int d = 0; d < 64; ++d) {
            float x = xs[a][d];
            float4 w0 = *(const float4*)&Ws[d][cb];
            float4 w1 = *(const float4*)&Ws[d][cb + 4];
            acc[0] += x * w0.x; acc[1] += x * w0.y; acc[2] += x * w0.z; acc[3] += x * w0.w;
            acc[4] += x * w1.x; acc[5] += x * w1.y; acc[6] += x * w1.z; acc[7] += x * w1.w;
        }
        #pragma unroll
        for (int j = 0; j < 8; ++j) hs[a][cb + j] = fmaxf(acc[j], 0.f);
        __syncthreads();
        // xs += adj @ hs   (each thread read-modify-writes only its own slice)
        float4 x0 = *(float4*)&xs[a][cb];
        float4 x1 = *(float4*)&xs[a][cb + 4];
        #pragma unroll 8
        for (int b = 0; b < NA; ++b) {
            float ad = adjS[a][b];
            float4 h0 = *(const float4*)&hs[b][cb];
            float4 h1 = *(const float4*)&hs[b][cb + 4];
            x0.x += ad * h0.x; x0.y += ad * h0.y; x0.z += ad * h0.z; x0.w += ad * h0.w;
            x1.x += ad * h1.x; x1.y += ad * h1.y; x1.z += ad * h1.z; x1.w += ad * h1.w;
        }
        *(float4*)&xs[a][cb] = x0;
        *(float4*)&xs[a][cb + 4] = x1;
    }
    __syncthreads();
    if (tid < 64) {
        float s = 0.f;
        for (int r = 0; r < NA; ++r) s += xs[r][tid];
        comp_int[n * 64 + tid] = s * (1.0f / 40.0f);
    }
}

// ======================= CNN (fused 3-layer per row-tile) =======================
#define BROWS 106
#define BCOLS 74

__device__ __forceinline__ void conv_pass(
    const float (*__restrict__ X)[BCOLS], float (*__restrict__ Y)[BCOLS],
    const float* __restrict__ Kl, float bias, int i0, int i1, int t0, int tid)
{
    const int c = tid & 63, rg = tid >> 6;
    for (int rbase = i0 + rg * 8; rbase < i1; rbase += 32) {
        float acc[8];
        #pragma unroll
        for (int j = 0; j < 8; ++j) acc[j] = bias;
        #pragma unroll
        for (int dc = 0; dc < 11; ++dc) {
            float s[18];
            #pragma unroll
            for (int t = 0; t < 18; ++t) s[t] = X[rbase - 5 + t][c + dc];
            #pragma unroll
            for (int dr = 0; dr < 11; ++dr) {
                float kv = Kl[dr * 11 + dc];
                #pragma unroll
                for (int j = 0; j < 8; ++j) acc[j] += kv * s[dr + j];
            }
        }
        #pragma unroll
        for (int j = 0; j < 8; ++j) {
            int i = rbase + j;
            if (i < i1) {
                int gr = t0 - 15 + i;
                Y[i][c + 5] = (gr >= 0 && gr < LP) ? fmaxf(acc[j], 0.f) : 0.f;
            }
        }
    }
}

__global__ __launch_bounds__(256) void cnn_kernel(
    const int* __restrict__ proteins, const float* __restrict__ embed_word,
    const float* __restrict__ K_cnn, const float* __restrict__ b_cnn,
    float* __restrict__ prot_part)
{
    __shared__ float bufA[BROWS][BCOLS];
    __shared__ float bufB[BROWS][BCOLS];
    __shared__ float Kl[121];
    __shared__ float red[4][64];
    const int tile = blockIdx.x, p = blockIdx.y;
    const int t0 = tile * 64, tid = threadIdx.x;

    // layer-0 input, zero margins everywhere (rows beyond 94 and 5-wide col pads)
    for (int j = tid; j < BROWS * BCOLS; j += 256) {
        int i = j / BCOLS, cc = j % BCOLS;
        int crel = cc - 5, gr = t0 - 15 + i;
        float v = 0.f;
        if (i < 94 && crel >= 0 && crel < 64 && gr >= 0 && gr < LP)
            v = embed_word[(size_t)proteins[p * LP + gr] * 64 + crel];
        bufA[i][cc] = v;
        bufB[i][cc] = 0.f;
    }
    if (tid < 121) Kl[tid] = K_cnn[tid];
    __syncthreads();
    conv_pass(bufA, bufB, Kl, b_cnn[0], 5, 89, t0, tid);   // L1: rows [t0-10, t0+74)
    __syncthreads();
    if (tid < 121) Kl[tid] = K_cnn[121 + tid];
    __syncthreads();
    conv_pass(bufB, bufA, Kl, b_cnn[1], 10, 84, t0, tid);  // L2: rows [t0-5, t0+69)
    __syncthreads();
    if (tid < 121) Kl[tid] = K_cnn[242 + tid];
    __syncthreads();

    // L3: rows [t0, t0+64) -> column sums
    const int c = tid & 63, rg = tid >> 6;
    float csum = 0.f;
    const float bias2 = b_cnn[2];
    for (int rbase = 15 + rg * 8; rbase < 79; rbase += 32) {
        float acc[8];
        #pragma unroll
        for (int j = 0; j < 8; ++j) acc[j] = bias2;
        #pragma unroll
        for (int dc = 0; dc < 11; ++dc) {
            float s[18];
            #pragma unroll
            for (int t = 0; t < 18; ++t) s[t] = bufA[rbase - 5 + t][c + dc];
            #pragma unroll
            for (int dr = 0; dr < 11; ++dr) {
                float kv = Kl[dr * 11 + dc];
                #pragma unroll
                for (int j = 0; j < 8; ++j) acc[j] += kv * s[dr + j];
            }
        }
        #pragma unroll
        for (int j = 0; j < 8; ++j)
            if (rbase + j < 79) csum += fmaxf(acc[j], 0.f);
    }
    red[rg][c] = csum;
    __syncthreads();
    if (tid < 64)
        prot_part[((size_t)p * 8 + tile) * 64 + tid] =
            red[0][tid] + red[1][tid] + red[2][tid] + red[3][tid];
}

__global__ void cnn_reduce(const float* __restrict__ prot_part, float* __restrict__ prot_int)
{
    const int p = blockIdx.x, c = threadIdx.x;
    float s = 0.f;
    for (int t = 0; t < 8; ++t) s += prot_part[((size_t)p * 8 + t) * 64 + c];
    prot_int[p * 64 + c] = s * (1.0f / 512.0f);
}

// ======================= GCN: split-K GEMM (N=64) + epilogue =======================
__global__ __launch_bounds__(256) void spk_gemm64(
    const float* __restrict__ A, const float* __restrict__ X,
    float* __restrict__ part, int M, int kchunk)
{
    __shared__ float As[64][17];
    __shared__ float Xs[16][64];
    const int rb = blockIdx.x * 64;
    const int s = blockIdx.y;
    const int k0 = s * kchunk;
    const int k1 = (k0 + kchunk < M) ? (k0 + kchunk) : M;
    const int tid = threadIdx.x, tx = tid & 15, ty = tid >> 4;
    float acc[4][4] = {};
    for (int kb = k0; kb < k1; kb += 16) {
        #pragma unroll
        for (int q = 0; q < 4; ++q) {
            int r = (tid >> 4) + q * 16, kc = tid & 15;
            int row = rb + r, kidx = kb + kc;
            As[r][kc] = (row < M && kidx < k1) ? A[(size_t)row * M + kidx] : 0.f;
        }
        #pragma unroll
        for (int q = 0; q < 4; ++q) {
            int kr = (tid >> 6) + q * 4, cc = tid & 63;
            int kidx = kb + kr;
            Xs[kr][cc] = (kidx < k1) ? X[(size_t)kidx * 64 + cc] : 0.f;
        }
        __syncthreads();
        #pragma unroll
        for (int kk = 0; kk < 16; ++kk) {
            float a0 = As[ty * 4 + 0][kk], a1 = As[ty * 4 + 1][kk];
            float a2 = As[ty * 4 + 2][kk], a3 = As[ty * 4 + 3][kk];
            float4 b4 = *(const float4*)&Xs[kk][tx * 4];
            acc[0][0] += a0 * b4.x; acc[0][1] += a0 * b4.y; acc[0][2] += a0 * b4.z; acc[0][3] += a0 * b4.w;
            acc[1][0] += a1 * b4.x; acc[1][1] += a1 * b4.y; acc[1][2] += a1 * b4.z; acc[1][3] += a1 * b4.w;
            acc[2][0] += a2 * b4.x; acc[2][1] += a2 * b4.y; acc[2][2] += a2 * b4.z; acc[2][3] += a2 * b4.w;
            acc[3][0] += a3 * b4.x; acc[3][1] += a3 * b4.y; acc[3][2] += a3 * b4.z; acc[3][3] += a3 * b4.w;
        }
        __syncthreads();
    }
    #pragma unroll
    for (int i = 0; i < 4; ++i) {
        int row = rb + ty * 4 + i;
        if (row < M)
            *(float4*)&part[((size_t)s * M + row) * 64 + tx * 4] =
                make_float4(acc[i][0], acc[i][1], acc[i][2], acc[i][3]);
    }
}

__global__ __launch_bounds__(256) void gcn_epi(
    const float* __restrict__ part, int S, int M,
    const float* __restrict__ W, const float* __restrict__ bias,
    float* __restrict__ Xout)
{
    __shared__ float Ys[64][68];
    __shared__ float Ws[64][64];
    const int rb = blockIdx.x * 64;
    const int tid = threadIdx.x;
    for (int j = tid; j < 4096; j += 256) Ws[j >> 6][j & 63] = W[j];
    for (int j = tid; j < 4096; j += 256) {
        int r = j >> 6, c = j & 63;
        float sum = 0.f;
        if (rb + r < M)
            for (int t = 0; t < S; ++t) sum += part[((size_t)t * M + rb + r) * 64 + c];
        Ys[r][c] = sum;
    }
    __syncthreads();
    const int tx = tid & 15, ty = tid >> 4;
    float acc[4][4];
    #pragma unroll
    for (int i = 0; i < 4; ++i)
        #pragma unroll
        for (int j = 0; j < 4; ++j) acc[i][j] = bias[tx * 4 + j];
    for (int d = 0; d < 64; ++d) {
        float a0 = Ys[ty * 4 + 0][d], a1 = Ys[ty * 4 + 1][d];
        float a2 = Ys[ty * 4 + 2][d], a3 = Ys[ty * 4 + 3][d];
        float4 w4 = *(const float4*)&Ws[d][tx * 4];
        acc[0][0] += a0 * w4.x; acc[0][1] += a0 * w4.y; acc[0][2] += a0 * w4.z; acc[0][3] += a0 * w4.w;
        acc[1][0] += a1 * w4.x; acc[1][1] += a1 * w4.y; acc[1][2] += a1 * w4.z; acc[1][3] += a1 * w4.w;
        acc[2][0] += a2 * w4.x; acc[2][1] += a2 * w4.y; acc[2][2] += a2 * w4.z; acc[2][3] += a2 * w4.w;
        acc[3][0] += a3 * w4.x; acc[3][1] += a3 * w4.y; acc[3][2] += a3 * w4.z; acc[3][3] += a3 * w4.w;
    }
    #pragma unroll
    for (int i = 0; i < 4; ++i) {
        int row = rb + ty * 4 + i;
        if (row < M)
            #pragma unroll
            for (int j = 0; j < 4; ++j)
                Xout[(size_t)row * 64 + tx * 4 + j] = fmaxf(acc[i][j], 0.f);
    }
}

// ======================= generic GEMM + bias + relu (opt. row gather) =======================
template<bool GATHER>
__global__ __launch_bounds__(256) void gemm_bias_relu(
    const float* __restrict__ A, int lda, const int* __restrict__ idx,
    const float* __restrict__ Bm, const float* __restrict__ bias,
    float* __restrict__ C, int M, int N, int K)
{
    __shared__ float As[64][17];
    __shared__ float Bs[16][64];
    const int rb = blockIdx.x * 64, nb = blockIdx.y * 64;
    const int tid = threadIdx.x, tx = tid & 15, ty = tid >> 4;
    float acc[4][4] = {};
    for (int kb = 0; kb < K; kb += 16) {
        #pragma unroll
        for (int q = 0; q < 4; ++q) {
            int r = (tid >> 4) + q * 16, kc = tid & 15;
            int row = rb + r;
            float v = 0.f;
            if (row < M) {
                size_t ar = GATHER ? (size_t)idx[row] : (size_t)row;
                v = A[ar * lda + kb + kc];
            }
            As[r][kc] = v;
        }
        #pragma unroll
        for (int q = 0; q < 4; ++q) {
            int kr = (tid >> 6) + q * 4, cc = tid & 63;
            Bs[kr][cc] = Bm[(size_t)(kb + kr) * N + nb + cc];
        }
        __syncthreads();
        #pragma unroll
        for (int kk = 0; kk < 16; ++kk) {
            float a0 = As[ty * 4 + 0][kk], a1 = As[ty * 4 + 1][kk];
            float a2 = As[ty * 4 + 2][kk], a3 = As[ty * 4 + 3][kk];
            float4 b4 = *(const float4*)&Bs[kk][tx * 4];
            acc[0][0] += a0 * b4.x; acc[0][1] += a0 * b4.y; acc[0][2] += a0 * b4.z; acc[0][3] += a0 * b4.w;
            acc[1][0] += a1 * b4.x; acc[1][1] += a1 * b4.y; acc[1][2] += a1 * b4.z; acc[1][3] += a1 * b4.w;
            acc[2][0] += a2 * b4.x; acc[2][1] += a2 * b4.y; acc[2][2] += a2 * b4.z; acc[2][3] += a2 * b4.w;
            acc[3][0] += a3 * b4.x; acc[3][1] += a3 * b4.y; acc[3][2] += a3 * b4.z; acc[3][3] += a3 * b4.w;
        }
        __syncthreads();
    }
    #pragma unroll
    for (int i = 0; i < 4; ++i) {
        int row = rb + ty * 4 + i;
        if (row < M)
            #pragma unroll
            for (int j = 0; j < 4; ++j) {
                int col = nb + tx * 4 + j;
                C[(size_t)row * N + col] = fmaxf(acc[i][j] + bias[col], 0.f);
            }
    }
}

// ======================= concat + final head =======================
__global__ void concat_kernel(
    const int* __restrict__ idx_c, const int* __restrict__ idx_p,
    const float* __restrict__ comp_int, const float* __restrict__ Xc,
    const float* __restrict__ fd3, const float* __restrict__ prot_int,
    const float* __restrict__ Xp, const float* __restrict__ fp3,
    float* __restrict__ cat)
{
    int j = blockIdx.x * 256 + threadIdx.x;
    if (j >= BSZ * 384) return;
    int r = j / 384, c = j % 384;
    float v;
    if (c < 64)       v = comp_int[(size_t)idx_c[r] * 64 + c];
    else if (c < 128) v = Xc[(size_t)idx_c[r] * 64 + (c - 64)];
    else if (c < 192) v = fd3[(size_t)r * 64 + (c - 128)];
    else if (c < 256) v = prot_int[(size_t)idx_p[r] * 64 + (c - 192)];
    else if (c < 320) v = Xp[(size_t)idx_p[r] * 64 + (c - 256)];
    else              v = fp3[(size_t)r * 64 + (c - 320)];
    cat[j] = v;
}

__global__ void head_final(
    const float* __restrict__ h3, const float* __restrict__ W_int,
    const float* __restrict__ b_int, float* __restrict__ out)
{
    int r = blockIdx.x * 256 + threadIdx.x;
    if (r >= BSZ) return;
    float s0 = b_int[0], s1 = b_int[1];
    for (int k = 0; k < 256; ++k) {
        float h = h3[(size_t)r * 256 + k];
        s0 += h * W_int[k * 2 + 0];
        s1 += h * W_int[k * 2 + 1];
    }
    out[r * 2 + 0] = 1.f / (1.f + expf(-s0));
    out[r * 2 + 1] = 1.f / (1.f + expf(-s1));
}

// ======================= launch =======================
extern "C" void kernel_launch(void* const* d_in, const int* in_sizes, int n_in,
                              void* d_out, int out_size, void* d_ws, size_t ws_size,
                              hipStream_t stream)
{
    const int*   idx_c        = (const int*)  d_in[0];
    const int*   idx_p        = (const int*)  d_in[1];
    const int*   compounds    = (const int*)  d_in[2];
    const int*   proteins     = (const int*)  d_in[3];
    const float* adjacencies  = (const float*)d_in[4];
    const float* A_c          = (const float*)d_in[5];
    const float* A_p          = (const float*)d_in[6];
    const float* embed_fp     = (const float*)d_in[7];
    const float* embed_word   = (const float*)d_in[8];
    const float* Xs_c         = (const float*)d_in[9];
    const float* Xs_p         = (const float*)d_in[10];
    const float* drug_feat    = (const float*)d_in[11];
    const float* protein_feat = (const float*)d_in[12];
    const float* W_gnn        = (const float*)d_in[13];
    const float* b_gnn        = (const float*)d_in[14];
    const float* K_cnn        = (const float*)d_in[15];
    const float* b_cnn        = (const float*)d_in[16];
    const float* W_gcn_d      = (const float*)d_in[17];
    const float* b_gcn_d      = (const float*)d_in[18];
    const float* W_gcn_p      = (const float*)d_in[19];
    const float* b_gcn_p      = (const float*)d_in[20];
    const float* Wd1 = (const float*)d_in[21]; const float* bd1 = (const float*)d_in[22];
    const float* Wd2 = (const float*)d_in[23]; const float* bd2 = (const float*)d_in[24];
    const float* Wd3 = (const float*)d_in[25]; const float* bd3 = (const float*)d_in[26];
    const float* Wp1 = (const float*)d_in[27]; const float* bp1 = (const float*)d_in[28];
    const float* Wp2 = (const float*)d_in[29]; const float* bp2 = (const float*)d_in[30];
    const float* Wp3 = (const float*)d_in[31]; const float* bp3 = (const float*)d_in[32];
    const float* Wo1 = (const float*)d_in[33]; const float* bo1 = (const float*)d_in[34];
    const float* Wo2 = (const float*)d_in[35]; const float* bo2 = (const float*)d_in[36];
    const float* Wo3 = (const float*)d_in[37]; const float* bo3 = (const float*)d_in[38];
    const float* W_int = (const float*)d_in[39]; const float* b_int = (const float*)d_in[40];

    float* ws = (float*)d_ws;
    float* comp_int  = ws; ws += NC * 64;
    float* prot_part = ws; ws += NP * 8 * 64;
    float* prot_int  = ws; ws += NP * 64;
    float* gcn_part  = ws; ws += 8 * NC * 64;
    float* Xc_a = ws; ws += NC * 64;
    float* Xc_b = ws; ws += NC * 64;
    float* Xp_a = ws; ws += NP * 64;
    float* Xp_b = ws; ws += NP * 64;
    float* fd1 = ws; ws += BSZ * 128;
    float* fd2 = ws; ws += BSZ * 64;
    float* fd3 = ws; ws += BSZ * 64;
    float* fp1 = ws; ws += BSZ * 128;
    float* fp2 = ws; ws += BSZ * 64;
    float* fp3 = ws; ws += BSZ * 64;
    float* cat = ws; ws += BSZ * 384;
    float* h1  = ws; ws += BSZ * 256;
    float* h2  = ws; ws += BSZ * 256;
    float* h3  = ws; ws += BSZ * 256;
    (void)ws_size; (void)in_sizes; (void)n_in; (void)out_size;

    // branch 1: compound GNN
    gnn_kernel<<<NC, 320, 0, stream>>>(compounds, adjacencies, embed_fp, W_gnn, b_gnn, comp_int);
    // branch 2: protein CNN
    cnn_kernel<<<dim3(8, NP), 256, 0, stream>>>(proteins, embed_word, K_cnn, b_cnn, prot_part);
    cnn_reduce<<<NP, 64, 0, stream>>>(prot_part, prot_int);
    // branch 3: GCN drug
    spk_gemm64<<<dim3(32, 8), 256, 0, stream>>>(A_c, Xs_c, gcn_part, NC, 256);
    gcn_epi<<<32, 256, 0, stream>>>(gcn_part, 8, NC, W_gcn_d, b_gcn_d, Xc_a);
    spk_gemm64<<<dim3(32, 8), 256, 0, stream>>>(A_c, Xc_a, gcn_part, NC, 256);
    gcn_epi<<<32, 256, 0, stream>>>(gcn_part, 8, NC, W_gcn_d + 4096, b_gcn_d + 64, Xc_b);
    // branch 3b: GCN protein
    spk_gemm64<<<dim3(24, 8), 256, 0, stream>>>(A_p, Xs_p, gcn_part, NP, 192);
    gcn_epi<<<24, 256, 0, stream>>>(gcn_part, 8, NP, W_gcn_p, b_gcn_p, Xp_a);
    spk_gemm64<<<dim3(24, 8), 256, 0, stream>>>(A_p, Xp_a, gcn_part, NP, 192);
    gcn_epi<<<24, 256, 0, stream>>>(gcn_part, 8, NP, W_gcn_p + 4096, b_gcn_p + 64, Xp_b);
    // branch 4: drug MLP
    gemm_bias_relu<true ><<<dim3(64, 2), 256, 0, stream>>>(drug_feat, 1024, idx_c, Wd1, bd1, fd1, BSZ, 128, 1024);
    gemm_bias_relu<false><<<dim3(64, 1), 256, 0, stream>>>(fd1, 128, nullptr, Wd2, bd2, fd2, BSZ, 64, 128);
    gemm_bias_relu<false><<<dim3(64, 1), 256, 0, stream>>>(fd2, 64, nullptr, Wd3, bd3, fd3, BSZ, 64, 64);
    // branch 5: protein MLP
    gemm_bias_relu<true ><<<dim3(64, 2), 256, 0, stream>>>(protein_feat, 1024, idx_p, Wp1, bp1, fp1, BSZ, 128, 1024);
    gemm_bias_relu<false><<<dim3(64, 1), 256, 0, stream>>>(fp1, 128, nullptr, Wp2, bp2, fp2, BSZ, 64, 128);
    gemm_bias_relu<false><<<dim3(64, 1), 256, 0, stream>>>(fp2, 64, nullptr, Wp3, bp3, fp3, BSZ, 64, 64);
    // head
    concat_kernel<<<(BSZ * 384 + 255) / 256, 256, 0, stream>>>(idx_c, idx_p, comp_int, Xc_b, fd3, prot_int, Xp_b, fp3, cat);
    gemm_bias_relu<false><<<dim3(64, 4), 256, 0, stream>>>(cat, 384, nullptr, Wo1, bo1, h1, BSZ, 256, 384);
    gemm_bias_relu<false><<<dim3(64, 4), 256, 0, stream>>>(h1, 256, nullptr, Wo2, bo2, h2, BSZ, 256, 256);
    gemm_bias_relu<false><<<dim3(64, 4), 256, 0, stream>>>(h2, 256, nullptr, Wo3, bo3, h3, BSZ, 256, 256);
    head_final<<<(BSZ + 255) / 256, 256, 0, stream>>>(h3, W_int, b_int, (float*)d_out);
}